// Round 4
// baseline (620.328 us; speedup 1.0000x reference)
//
#include <hip/hip_runtime.h>
#include <math.h>
#include <stdint.h>

// Problem constants
#define BB    32
#define CIN   64
#define HH    32
#define WW    32
#define COUT  128
#define PP    1024      // HH*WW
#define OTILE 8         // output channels per block
#define PTILE 256       // pixels per block (4 waves x 64 px)

// inv_denom = 1/(2*1.5*0.025) = 13.3333, shift = 0.1*inv_denom = 1.3333
// Work in log2 domain: Z = (x - theta)*SCALE where SCALE = inv_denom*log2(e).
static constexpr float SCALE    = 19.235933878519513f;   // inv_denom * log2(e)
static constexpr float SBITS    = 1.9235933878519513f;   // shift * log2(e)
static constexpr float M2N      = 0.26359713811572677f;  // 2^-SBITS = e^-shift
static constexpr float OUTSCALE = 2.7025482032898827e-05f; // ALPHA*R*ln2^2
static constexpr float ZCUT     = 5.0f;   // skip term if all lanes Z < -5; residual <= ~1.2 in sum-units vs budget ~75

// Pre-pass: per (o,c) group, pre-scale theta*SCALE, stuff k into the 4 low
// mantissa bits, sort the 9 values ascending. Stuffing perturbs Z by <=1e-3
// (f-slope <= 2*SBITS => <=4e-3 per term) — negligible vs threshold budget.
__global__ __launch_bounds__(256) void sort_theta_kernel(
    const float* __restrict__ theta, float* __restrict__ ws)
{
    int g = blockIdx.x * 256 + threadIdx.x;   // g = o*CIN + c  (matches theta layout)
    if (g >= COUT * CIN) return;
    const float* tg = theta + (size_t)g * 9;
    float v[9];
#pragma unroll
    for (int k = 0; k < 9; ++k) {
        float s = tg[k] * SCALE;
        v[k] = __uint_as_float((__float_as_uint(s) & ~15u) | (uint32_t)k);
    }
    // insertion sort ascending (float compare: handles negatives correctly)
    for (int i = 1; i < 9; ++i) {
        float key = v[i];
        int j = i - 1;
        while (j >= 0 && v[j] > key) { v[j + 1] = v[j]; --j; }
        v[j + 1] = key;
    }
    float* og = ws + (size_t)g * 9;
#pragma unroll
    for (int j = 0; j < 9; ++j) og[j] = v[j];
}

__global__ __launch_bounds__(256) void nlconv_kernel(
    const float* __restrict__ x,     // [B, CIN, 32, 32]
    const float* __restrict__ ws,    // sorted prescaled theta groups [(o*CIN+c)*9]
    float* __restrict__ out)         // [B, COUT, 32, 32]
{
    // This block's o-tile of sorted thetas: [ (ol*CIN + c)*9 + j ]
    __shared__ float sth[OTILE * CIN * 9];      // 18432 B
    // lane-private 9-float patch so bodies can index xi[k] with dynamic k
    // stride 9 dwords: lanes hit banks (9t+k)%32 -> ~2 lanes/bank = free
    __shared__ float sxi[PTILE * 9];            // 9216 B

    const int t  = threadIdx.x;
    const int b  = blockIdx.x;
    const int pt = blockIdx.y;
    const int ot = blockIdx.z;
    const int p  = pt * PTILE + t;
    const int py = p >> 5;
    const int px = p & 31;
    const int o0 = ot * OTILE;

    // stage this o-tile's sorted thetas (contiguous in ws) into LDS
    {
        const float* src = ws + (size_t)o0 * CIN * 9;
#pragma unroll
        for (int i = t; i < OTILE * CIN * 9; i += PTILE) sth[i] = src[i];
    }
    __syncthreads();

    float* myx = sxi + t * 9;

    int   off[9];
    float msc[9];
#pragma unroll
    for (int dy = 0; dy < 3; ++dy) {
#pragma unroll
        for (int dx = 0; dx < 3; ++dx) {
            int yy = py + dy - 1;
            int xx = px + dx - 1;
            bool ok = (yy >= 0) && (yy < HH) && (xx >= 0) && (xx < WW);
            int yc = min(max(yy, 0), HH - 1);
            int xc = min(max(xx, 0), WW - 1);
            off[dy * 3 + dx] = yc * WW + xc;
            msc[dy * 3 + dx] = ok ? SCALE : 0.0f;   // pad -> xi = 0 (true padded value)
        }
    }

    const float* xb = x + (size_t)b * (CIN * PP);

    float acc[OTILE];
#pragma unroll
    for (int i = 0; i < OTILE; ++i) acc[i] = 0.0f;

    // prime pipeline (c = 0); xi pre-scaled into Z units
    float xi[9];
#pragma unroll
    for (int k = 0; k < 9; ++k) xi[k] = xb[off[k]] * msc[k];

    for (int c = 0; c < CIN; ++c) {
        // prefetch next channel's patch
        const float* xcn = xb + (size_t)min(c + 1, CIN - 1) * PP;
        float xn[9];
#pragma unroll
        for (int k = 0; k < 9; ++k) xn[k] = xcn[off[k]] * msc[k];

        // stash current patch for dynamic-k access (lane-private; no sync needed)
#pragma unroll
        for (int k = 0; k < 9; ++k) myx[k] = xi[k];

        // wave-max over 9 offsets x 64 lanes (in Z units)
        float m = xi[0];
#pragma unroll
        for (int k = 1; k < 9; ++k) m = fmaxf(m, xi[k]);
#pragma unroll
        for (int s = 32; s > 0; s >>= 1)
            m = fmaxf(m, __shfl_xor(m, s));

        // term active iff thetaS < cutS  (else all lanes have Z < -ZCUT)
        const float cutS = m + ZCUT;

#pragma unroll
        for (int ol = 0; ol < OTILE; ++ol) {
            const float* gth = sth + (ol * CIN + c) * 9;

            // count of sorted thetas below the wave cut
            int cnt = 0;
#pragma unroll
            for (int j = 0; j < 9; ++j) cnt += (gth[j] < cutS) ? 1 : 0;

            // OPAQUE trip count: SGPR the optimizer cannot bound -> the loop
            // must remain a real loop (no unroll-by-bound, no if-conversion).
            cnt = __builtin_amdgcn_readfirstlane(cnt);
            asm volatile("" : "+s"(cnt));

            float a = acc[ol];
            // pipelined: theta for j+1 prefetched during iteration j
            float thv = gth[0];
#pragma unroll 1
            for (int j = 0; j < cnt; ++j) {
                float thn = gth[min(j + 1, 8)];
                uint32_t tb = __float_as_uint(thv);
                int   k   = (int)(tb & 15u);
                float xik = myx[k];                        // ds_read, dynamic k
                float Zr  = xik - thv;                     // Z in log2 units
                float Zc  = fminf(Zr, 60.0f);              // overflow clamp
                float E   = __builtin_amdgcn_exp2f(Zc);    // 2^Z
                float n1  = 1.0f + E;
                float n2  = fmaf(E, M2N, 1.0f);            // 1 + 2^(Z-SBITS)
                float sp1 = __builtin_amdgcn_logf(n1);     // softplus(z)/ln2
                float sp2 = __builtin_amdgcn_logf(n2);     // softplus(z-s)/ln2
                float tv  = (sp1 - sp2) * (sp1 + sp2);     // sp1^2 - sp2^2
                float tL  = fmaf(2.0f * SBITS, Zr, -SBITS * SBITS); // exact linear tail
                tv = (Zr > 24.0f) ? tL : tv;
                a += tv;
                thv = thn;
            }
            acc[ol] = a;
        }

#pragma unroll
        for (int k = 0; k < 9; ++k) xi[k] = xn[k];
    }

    float* ob = out + ((size_t)b * COUT + o0) * PP + p;
#pragma unroll
    for (int o = 0; o < OTILE; ++o) {
        float v = acc[o] * OUTSCALE;
        v = fminf(fmaxf(v, 0.0f), 9.0f);
        ob[(size_t)o * PP] = v;
    }
}

extern "C" void kernel_launch(void* const* d_in, const int* in_sizes, int n_in,
                              void* d_out, int out_size, void* d_ws, size_t ws_size,
                              hipStream_t stream) {
    const float* x     = (const float*)d_in[0];  // [32,64,32,32]
    const float* theta = (const float*)d_in[1];  // [128,64,3,3]
    float* out         = (float*)d_out;          // [32,128,32,32]
    float* ws          = (float*)d_ws;           // 8192 groups x 9 floats = 288 KB

    sort_theta_kernel<<<dim3((COUT * CIN + 255) / 256), dim3(256), 0, stream>>>(theta, ws);

    dim3 grid(BB, PP / PTILE, COUT / OTILE);     // 32 x 4 x 16 = 2048 blocks
    dim3 block(256);
    nlconv_kernel<<<grid, block, 0, stream>>>(x, ws, out);
}

// Round 5
// 482.673 us; speedup vs baseline: 1.2852x; 1.2852x over previous
//
#include <hip/hip_runtime.h>
#include <math.h>
#include <stdint.h>

// Problem constants
#define BB    32
#define CIN   64
#define HH    32
#define WW    32
#define COUT  128
#define PP    1024      // HH*WW
#define OTILE 8         // output channels per block
#define PTILE 256       // pixels per block (4 waves x 64 px = 8 rows)
#define NPAD  10        // sorted theta list padded to 10 (even, >=9)

// inv_denom = 1/(2*1.5*0.025) = 13.3333, shift = 0.1*inv_denom = 1.3333
// Log2 domain: Z = (x - theta)*SCALE, SCALE = inv_denom*log2(e).
static constexpr float SCALE    = 19.235933878519513f;   // inv_denom * log2(e)
static constexpr float SBITS    = 1.9235933878519513f;   // shift * log2(e)
static constexpr float M2N      = 0.26359713811572677f;  // 2^-SBITS = e^-shift
static constexpr float OUTSCALE = 2.7025482032898827e-05f; // ALPHA*R*ln2^2
static constexpr float ZCUT     = 4.0f;   // skip if all lanes Z < -4: worst-case residual 576*f(-4)*OUTSCALE ~1.2e-4

// ---------------- P0: sort + prescale + pad theta ----------------
// ws layout: ws[(c*COUT + o)*NPAD + j]  (c-major so main staging is contiguous)
__global__ __launch_bounds__(256) void sort_theta_kernel(
    const float* __restrict__ theta, float* __restrict__ ws)
{
    int gid = blockIdx.x * 256 + threadIdx.x;   // o*CIN + c (theta layout)
    if (gid >= COUT * CIN) return;
    int o = gid >> 6, c = gid & 63;
    const float* tg = theta + (size_t)gid * 9;
    float v[NPAD];
#pragma unroll
    for (int k = 0; k < 9; ++k) {
        float s = tg[k] * SCALE;
        // stuff k into 4 low mantissa bits (<=16ulp -> <~0.04 per-term f error)
        v[k] = __uint_as_float((__float_as_uint(s) & ~15u) | (uint32_t)k);
    }
    // insertion sort ascending
    for (int i = 1; i < 9; ++i) {
        float key = v[i];
        int j = i - 1;
        while (j >= 0 && v[j] > key) { v[j + 1] = v[j]; --j; }
        v[j + 1] = key;
    }
    v[9] = __uint_as_float(__float_as_uint(1e30f) & ~15u);  // pad (k bits=0, in range)
    float* og = ws + (size_t)(c * COUT + o) * NPAD;
#pragma unroll
    for (int j = 0; j < NPAD; ++j) og[j] = v[j];
}

// ---------------- P1: per-(b, band, c) cut ----------------
// band m covers wave rows 2m,2m+1; window rows 2m-1..2m+2 clamped.
// bandcut[(b*16 + m)*64 + c] = max(window x, 0)*SCALE + ZCUT
__global__ __launch_bounds__(256) void bandcut_kernel(
    const float* __restrict__ x, float* __restrict__ bandcut)
{
    int t  = threadIdx.x;
    int bc = blockIdx.x;            // b*CIN + c
    const float4* xp = (const float4*)(x + (size_t)bc * PP);
    float4 v = xp[t];               // thread t: row t>>3, cols 4(t&7)..+3
    float m = fmaxf(fmaxf(v.x, v.y), fmaxf(v.z, v.w));
    m = fmaxf(m, __shfl_xor(m, 1));
    m = fmaxf(m, __shfl_xor(m, 2));
    m = fmaxf(m, __shfl_xor(m, 4));   // 8 threads of a row now all hold rowmax
    __shared__ float rmax[32];
    if ((t & 7) == 0) rmax[t >> 3] = m;
    __syncthreads();
    if (t < 16) {
        int r0 = max(2 * t - 1, 0), r3 = min(2 * t + 2, 31);
        float mm = rmax[r0];
        for (int r = r0 + 1; r <= r3; ++r) mm = fmaxf(mm, rmax[r]);
        mm = fmaxf(mm, 0.0f);         // zero-pad lanes contribute xi = 0
        int b = bc >> 6, c = bc & 63;
        bandcut[((b * 16 + t) << 6) + c] = fmaf(mm, SCALE, ZCUT);
    }
}

// ---------------- term body: sp^2(z) - sp^2(z-s), log2 units ----------------
__device__ __forceinline__ void term_body(float th, const float* myx, float& a)
{
    int   k   = (int)(__float_as_uint(th) & 15u);
    float xik = myx[k];                          // ds_read, dynamic k
    float Zr  = xik - th;
    float Zc  = fminf(Zr, 100.0f);
    float E   = __builtin_amdgcn_exp2f(Zc);      // 2^Z
    float n1  = 1.0f + E;
    float n2  = fmaf(E, M2N, 1.0f);
    float sp1 = __builtin_amdgcn_logf(n1);
    float sp2 = __builtin_amdgcn_logf(n2);
    float tv  = (sp1 - sp2) * (sp1 + sp2);       // sp1^2 - sp2^2
    // exact linear extension past the clamp: f(Z) = f(100) + 2*SBITS*(Z-100)
    tv = fmaf(2.0f * SBITS, fmaxf(Zr - 100.0f, 0.0f), tv);
    a += tv;                                     // pads: th=1e30 -> tv = 0 exactly
}

// ---------------- main kernel ----------------
__global__ __launch_bounds__(256) void nlconv_kernel(
    const float* __restrict__ x,        // [B, CIN, 32, 32]
    const float* __restrict__ ws,       // sorted padded thetas [c][o][NPAD]
    const float* __restrict__ bandcut,  // [b][band][c]
    float* __restrict__ out)            // [B, COUT, 32, 32]
{
    __shared__ float sth[CIN * OTILE * NPAD];   // [c][g][10] = 20480 B
    __shared__ float sxi[PTILE * 9];            // lane-private patches, 9216 B

    const int t  = threadIdx.x;
    const int b  = blockIdx.x;
    const int pt = blockIdx.y;
    const int ot = blockIdx.z;
    const int p  = pt * PTILE + t;
    const int py = p >> 5;
    const int px = p & 31;
    const int o0 = ot * OTILE;
    const int l  = t & 63;

    // stage this o-tile's sorted thetas: sth[c*80 + r] = ws[c*1280 + o0*10 + r]
    {
#pragma unroll
        for (int i = t; i < CIN * OTILE * NPAD; i += PTILE) {
            int c = i / (OTILE * NPAD);
            int r = i - c * (OTILE * NPAD);
            sth[i] = ws[(size_t)c * (COUT * NPAD) + o0 * NPAD + r];
        }
    }

    // this wave's band and its 64 channel-cuts (lane c holds cut[c])
    const int wv   = __builtin_amdgcn_readfirstlane(t >> 6);
    const int band = pt * 4 + wv;
    const float vcut = bandcut[(size_t)((b * 16 + band) << 6) + l];

    // spread-read lane mapping for the ballot count
    const int sprd1 = (l >> 3) * NPAD + (l & 7);   // g = l>>3, j = l&7
    const int sprd2 = (l & 7) * NPAD + 8;          // g = l&7,  j = 8

    int   off[9];
    float msc[9];
#pragma unroll
    for (int dy = 0; dy < 3; ++dy) {
#pragma unroll
        for (int dx = 0; dx < 3; ++dx) {
            int yy = py + dy - 1;
            int xx = px + dx - 1;
            bool ok = (yy >= 0) && (yy < HH) && (xx >= 0) && (xx < WW);
            int yc = min(max(yy, 0), HH - 1);
            int xc = min(max(xx, 0), WW - 1);
            off[dy * 3 + dx] = yc * WW + xc;
            msc[dy * 3 + dx] = ok ? SCALE : 0.0f;   // pad -> xi = 0
        }
    }

    const float* xb = x + (size_t)b * (CIN * PP);
    float* myx = sxi + t * 9;

    float acc[OTILE];
#pragma unroll
    for (int i = 0; i < OTILE; ++i) acc[i] = 0.0f;

    __syncthreads();   // sth ready

    // prime patch pipeline (c = 0)
    float xi[9];
#pragma unroll
    for (int k = 0; k < 9; ++k) xi[k] = xb[off[k]] * msc[k];

    for (int c = 0; c < CIN; ++c) {
        // prefetch next channel's patch
        const float* xcn = xb + (size_t)min(c + 1, CIN - 1) * PP;
        float xn[9];
#pragma unroll
        for (int k = 0; k < 9; ++k) xn[k] = xcn[off[k]] * msc[k];

        // stash current patch (lane-private, no sync needed)
#pragma unroll
        for (int k = 0; k < 9; ++k) myx[k] = xi[k];

        const int cbase = c * (OTILE * NPAD);

        // uniform per-c cut from the lane-spread register
        const float cutf = __uint_as_float(
            (uint32_t)__builtin_amdgcn_readlane((int)__float_as_uint(vcut), c));

        // one compare per lane covers all 8 groups x 8 slots; slot 8 via mB
        float f1 = sth[cbase + sprd1];
        float f2 = sth[cbase + sprd2];
        unsigned long long mA = __ballot(f1 < cutf);
        unsigned long long mB = __ballot(f2 < cutf);

#pragma unroll
        for (int g = 0; g < 8; ++g) {
            int cnt = (int)__popcll(mA & (0xFFull << (8 * g)))
                    + (int)((mB >> g) & 1ull);
            int np = (cnt + 1) >> 1;           // pair iterations
            asm volatile("" : "+s"(np));       // opaque: loop stays a real loop
            const float* gth = sth + cbase + g * NPAD;
            float a = acc[g];
#pragma unroll 1
            for (int j2 = 0; j2 < np; ++j2) {
                float tha = gth[2 * j2];       // ds_read_b64 pair
                float thb = gth[2 * j2 + 1];
                term_body(tha, myx, a);
                term_body(thb, myx, a);
            }
            acc[g] = a;
        }

#pragma unroll
        for (int k = 0; k < 9; ++k) xi[k] = xn[k];
    }

    float* ob = out + ((size_t)b * COUT + o0) * PP + p;
#pragma unroll
    for (int o = 0; o < OTILE; ++o) {
        float v = acc[o] * OUTSCALE;
        v = fminf(fmaxf(v, 0.0f), 9.0f);
        ob[(size_t)o * PP] = v;
    }
}

extern "C" void kernel_launch(void* const* d_in, const int* in_sizes, int n_in,
                              void* d_out, int out_size, void* d_ws, size_t ws_size,
                              hipStream_t stream) {
    const float* x     = (const float*)d_in[0];  // [32,64,32,32]
    const float* theta = (const float*)d_in[1];  // [128,64,3,3]
    float* out         = (float*)d_out;          // [32,128,32,32]

    float* ws_theta = (float*)d_ws;                              // 327,680 B
    float* ws_cut   = (float*)d_ws + (size_t)CIN * COUT * NPAD;  // 131,072 B

    sort_theta_kernel<<<dim3((COUT * CIN + 255) / 256), dim3(256), 0, stream>>>(theta, ws_theta);
    bandcut_kernel<<<dim3(BB * CIN), dim3(256), 0, stream>>>(x, ws_cut);

    dim3 grid(BB, PP / PTILE, COUT / OTILE);     // 32 x 4 x 16 = 2048 blocks
    nlconv_kernel<<<grid, dim3(256), 0, stream>>>(x, ws_theta, ws_cut, out);
}

// Round 6
// 381.437 us; speedup vs baseline: 1.6263x; 1.2654x over previous
//
#include <hip/hip_runtime.h>
#include <math.h>
#include <stdint.h>

// Problem constants
#define BB    32
#define CIN   64
#define HH    32
#define WW    32
#define COUT  128
#define PP    1024      // HH*WW
#define OTILE 8         // output channels per block
#define PTILE 256       // pixels per block (4 waves x 64 px = 8 rows)
#define NPAD  10        // sorted theta list padded to 10 (even, >=9)
#define TABN  160       // f-table knots
#define TABH  0.125f    // knot spacing in Z (log2 units)

// inv_denom = 1/(2*1.5*0.025) = 13.3333, shift = 0.1*inv_denom = 1.3333
// Log2 domain: Z = (x - theta)*SCALE, SCALE = inv_denom*log2(e).
static constexpr float  SCALE    = 19.235933878519513f;   // inv_denom * log2(e)
static constexpr float  SBITS    = 1.9235933878519513f;   // shift * log2(e)
static constexpr double M2Nd     = 0.26359713811572677;   // 2^-SBITS
static constexpr float  OUTSCALE = 2.7025482032898827e-05f; // ALPHA*R*ln2^2
static constexpr float  ZCUT     = 2.5f;  // skip if all lanes Z < -2.5: residual <= 576*alphaR*t(-2.5) ~ 1.9e-4
static constexpr float  ZLO      = -3.0f; // table start
static constexpr float  ZTOP     = 16.875f; // ZLO + 159*TABH; linear beyond (err ~ 8.06*Z*2^-Z < 1.1e-3)
static constexpr float  TWOS     = 3.8471867757039026f;   // 2*SBITS (asymptotic slope)
static constexpr float  INVH     = 8.0f;                  // 1/TABH
static constexpr float  IDXBIAS  = 24.0f;                 // -ZLO*INVH

// ---------------- P0: sort + prescale + pad theta ----------------
// ws layout: ws[(c*COUT + o)*NPAD + j]
__global__ __launch_bounds__(256) void sort_theta_kernel(
    const float* __restrict__ theta, float* __restrict__ ws)
{
    int gid = blockIdx.x * 256 + threadIdx.x;   // o*CIN + c (theta layout)
    if (gid >= COUT * CIN) return;
    int o = gid >> 6, c = gid & 63;
    const float* tg = theta + (size_t)gid * 9;
    float v[NPAD];
#pragma unroll
    for (int k = 0; k < 9; ++k) {
        float s = tg[k] * SCALE;
        // stuff k into 4 low mantissa bits (<=16ulp -> Z err <=2.4e-4 -> negligible)
        v[k] = __uint_as_float((__float_as_uint(s) & ~15u) | (uint32_t)k);
    }
    for (int i = 1; i < 9; ++i) {               // insertion sort ascending
        float key = v[i];
        int j = i - 1;
        while (j >= 0 && v[j] > key) { v[j + 1] = v[j]; --j; }
        v[j + 1] = key;
    }
    v[9] = __uint_as_float(__float_as_uint(1e30f) & ~15u);  // pad -> Z=-inf -> tv ~ f(-3) ~ 1.8e-7 out
    float* og = ws + (size_t)(c * COUT + o) * NPAD;
#pragma unroll
    for (int j = 0; j < NPAD; ++j) og[j] = v[j];
}

// ---------------- P1: per-(b, band, c) cut ----------------
__global__ __launch_bounds__(256) void bandcut_kernel(
    const float* __restrict__ x, float* __restrict__ bandcut)
{
    int t  = threadIdx.x;
    int bc = blockIdx.x;            // b*CIN + c
    const float4* xp = (const float4*)(x + (size_t)bc * PP);
    float4 v = xp[t];               // thread t: row t>>3, cols 4(t&7)..+3
    float m = fmaxf(fmaxf(v.x, v.y), fmaxf(v.z, v.w));
    m = fmaxf(m, __shfl_xor(m, 1));
    m = fmaxf(m, __shfl_xor(m, 2));
    m = fmaxf(m, __shfl_xor(m, 4));   // 8 threads of a row hold rowmax
    __shared__ float rmax[32];
    if ((t & 7) == 0) rmax[t >> 3] = m;
    __syncthreads();
    if (t < 16) {
        int r0 = max(2 * t - 1, 0), r3 = min(2 * t + 2, 31);
        float mm = rmax[r0];
        for (int r = r0 + 1; r <= r3; ++r) mm = fmaxf(mm, rmax[r]);
        mm = fmaxf(mm, 0.0f);         // zero-pad lanes contribute xi = 0
        int b = bc >> 6, c = bc & 63;
        bandcut[((b * 16 + t) << 6) + c] = fmaf(mm, SCALE, ZCUT);
    }
}

// ---------------- P2: f-table (duplicated pairs for ds_read_b64) ----------------
// tab[i] = ( f(ZLO + i*h), f(ZLO + (i+1)*h) ),  f in log2 units, fp64-evaluated
__global__ __launch_bounds__(256) void ftable_kernel(float2* __restrict__ tab)
{
    int i = threadIdx.x;
    if (i >= TABN) return;
    double Z0 = (double)ZLO + (double)TABH * i;
    double Z1 = Z0 + (double)TABH;
    auto fd = [](double Z) {
        double E = exp2(Z);
        double a = log2(1.0 + E);
        double b = log2(1.0 + E * M2Nd);
        return a * a - b * b;
    };
    tab[i] = make_float2((float)fd(Z0), (float)fd(Z1));
}

// ---------------- term body: table-lerp of f(Z), zero transcendentals ----------
__device__ __forceinline__ void term_body(float th, const float* myx,
                                          const float2* ftab, float& a)
{
    int   k   = (int)(__float_as_uint(th) & 15u);
    float xik = myx[k];                          // ds_read, dynamic k
    float Zr  = xik - th;
    float u   = fmaf(Zr, INVH, IDXBIAS);         // table coordinate
    u = fminf(fmaxf(u, 0.0f), 158.99f);          // med3 clamp, i <= 158
    int   i   = (int)u;                          // trunc == floor (u >= 0)
    float fr  = u - (float)i;
    float2 y  = ftab[i];                         // ds_read_b64
    float tv  = fmaf(fr, y.y - y.x, y.x);        // lerp
    float zt  = fmaxf(Zr - ZTOP, 0.0f);          // exact-asymptote tail
    tv = fmaf(TWOS, zt, tv);
    a += tv;                                     // pads: u clamps to 0 -> tv = f(-3) ~ 0
}

// ---------------- main kernel ----------------
__global__ __launch_bounds__(256) void nlconv_kernel(
    const float* __restrict__ x,        // [B, CIN, 32, 32]
    const float* __restrict__ ws,       // sorted padded thetas [c][o][NPAD]
    const float* __restrict__ bandcut,  // [b][band][c]
    const float2* __restrict__ ftabg,   // f-table pairs
    float* __restrict__ out)            // [B, COUT, 32, 32]
{
    __shared__ float  sth[CIN * OTILE * NPAD];   // 20480 B
    __shared__ float  sxi[PTILE * 9];            // lane-private patches, 9216 B
    __shared__ float2 ftab[TABN];                // 1280 B

    const int t  = threadIdx.x;
    const int b  = blockIdx.x;
    const int pt = blockIdx.y;
    const int ot = blockIdx.z;
    const int p  = pt * PTILE + t;
    const int py = p >> 5;
    const int px = p & 31;
    const int o0 = ot * OTILE;
    const int l  = t & 63;

    // stage sorted thetas + f-table
    {
#pragma unroll
        for (int i = t; i < CIN * OTILE * NPAD; i += PTILE) {
            int c = i / (OTILE * NPAD);
            int r = i - c * (OTILE * NPAD);
            sth[i] = ws[(size_t)c * (COUT * NPAD) + o0 * NPAD + r];
        }
        if (t < TABN) ftab[t] = ftabg[t];
    }

    // this wave's band and its 64 channel-cuts (lane c holds cut[c])
    const int wv   = __builtin_amdgcn_readfirstlane(t >> 6);
    const int band = pt * 4 + wv;
    const float vcut = bandcut[(size_t)((b * 16 + band) << 6) + l];

    // spread-read lane mapping for the ballot count
    const int sprd1 = (l >> 3) * NPAD + (l & 7);   // g = l>>3, j = l&7
    const int sprd2 = (l & 7) * NPAD + 8;          // g = l&7,  j = 8

    int   off[9];
    float msc[9];
#pragma unroll
    for (int dy = 0; dy < 3; ++dy) {
#pragma unroll
        for (int dx = 0; dx < 3; ++dx) {
            int yy = py + dy - 1;
            int xx = px + dx - 1;
            bool ok = (yy >= 0) && (yy < HH) && (xx >= 0) && (xx < WW);
            int yc = min(max(yy, 0), HH - 1);
            int xc = min(max(xx, 0), WW - 1);
            off[dy * 3 + dx] = yc * WW + xc;
            msc[dy * 3 + dx] = ok ? SCALE : 0.0f;   // pad -> xi = 0
        }
    }

    const float* xb = x + (size_t)b * (CIN * PP);
    float* myx = sxi + t * 9;

    float acc[OTILE];
#pragma unroll
    for (int i = 0; i < OTILE; ++i) acc[i] = 0.0f;

    __syncthreads();   // sth + ftab ready

    // prime: stash c=0 patch
    {
#pragma unroll
        for (int k = 0; k < 9; ++k) myx[k] = xb[off[k]] * msc[k];
    }

    for (int c = 0; c < CIN; ++c) {
        // prefetch next channel's patch into registers (VMEM overlaps bodies)
        const float* xcn = xb + (size_t)min(c + 1, CIN - 1) * PP;
        float xn[9];
#pragma unroll
        for (int k = 0; k < 9; ++k) xn[k] = xcn[off[k]] * msc[k];

        const int cbase = c * (OTILE * NPAD);

        // uniform per-c cut from the lane-spread register
        const float cutf = __uint_as_float(
            (uint32_t)__builtin_amdgcn_readlane((int)__float_as_uint(vcut), c));

        // one compare per lane covers all 8 groups x 8 slots; slot 8 via mB
        float f1 = sth[cbase + sprd1];
        float f2 = sth[cbase + sprd2];
        unsigned long long mA = __ballot(f1 < cutf);
        unsigned long long mB = __ballot(f2 < cutf);

#pragma unroll
        for (int g = 0; g < 8; ++g) {
            int cnt = (int)__popcll(mA & (0xFFull << (8 * g)))
                    + (int)((mB >> g) & 1ull);
            int np = (cnt + 1) >> 1;           // pair iterations
            asm volatile("" : "+s"(np));       // opaque: loop stays a real loop
            const float* gth = sth + cbase + g * NPAD;
            float a = acc[g];
#pragma unroll 1
            for (int j2 = 0; j2 < np; ++j2) {
                float tha = gth[2 * j2];       // ds_read_b64 pair
                float thb = gth[2 * j2 + 1];
                term_body(tha, myx, ftab, a);
                term_body(thb, myx, ftab, a);
            }
            acc[g] = a;
        }

        // stash next patch after bodies consumed the current one (wave-private)
#pragma unroll
        for (int k = 0; k < 9; ++k) myx[k] = xn[k];
    }

    float* ob = out + ((size_t)b * COUT + o0) * PP + p;
#pragma unroll
    for (int o = 0; o < OTILE; ++o) {
        float v = acc[o] * OUTSCALE;
        v = fminf(fmaxf(v, 0.0f), 9.0f);
        ob[(size_t)o * PP] = v;
    }
}

extern "C" void kernel_launch(void* const* d_in, const int* in_sizes, int n_in,
                              void* d_out, int out_size, void* d_ws, size_t ws_size,
                              hipStream_t stream) {
    const float* x     = (const float*)d_in[0];  // [32,64,32,32]
    const float* theta = (const float*)d_in[1];  // [128,64,3,3]
    float* out         = (float*)d_out;          // [32,128,32,32]

    float*  ws_theta = (float*)d_ws;                               // 327,680 B
    float*  ws_cut   = ws_theta + (size_t)CIN * COUT * NPAD;       // 131,072 B
    float2* ws_tab   = (float2*)(ws_cut + (size_t)BB * 16 * 64);   //   1,280 B

    sort_theta_kernel<<<dim3((COUT * CIN + 255) / 256), dim3(256), 0, stream>>>(theta, ws_theta);
    bandcut_kernel<<<dim3(BB * CIN), dim3(256), 0, stream>>>(x, ws_cut);
    ftable_kernel<<<dim3(1), dim3(256), 0, stream>>>(ws_tab);

    dim3 grid(BB, PP / PTILE, COUT / OTILE);     // 32 x 4 x 16 = 2048 blocks
    nlconv_kernel<<<grid, dim3(256), 0, stream>>>(x, ws_theta, ws_cut, ws_tab, out);
}

// Round 7
// 306.262 us; speedup vs baseline: 2.0255x; 1.2455x over previous
//
#include <hip/hip_runtime.h>
#include <math.h>
#include <stdint.h>

// Problem constants
#define BB    32
#define CIN   64
#define HH    32
#define WW    32
#define COUT  128
#define PP    1024      // HH*WW
#define OTILE 8         // output channels per block
#define PTILE 256       // pixels per block (4 waves x 64 px = 8 rows)
#define NPAD  12        // sorted theta list padded to 12 (3 pairs headroom)
#define TABN  160       // f-table knots
#define TROW  36        // tile row stride (34 cols + 2 slack)
#define TWSZ  148       // per-wave tile dwords (4*36 + dump + pad)

// Log2 domain: Z = (x - theta)*SCALEE, SCALEE = inv_denom*log2(e) = 19.2359
// Table coordinate u = (Z - ZLO)/h = 8Z + 24 = x*MSC8 + thp, thp = 24 - theta*MSC8
static constexpr float  SCALEE   = 19.235933878519513f;
static constexpr float  MSC8     = 153.88747102815611f;   // SCALEE * 8
static constexpr double M2Nd     = 0.26359713811572677;   // 2^-SBITS
static constexpr float  OUTSCALE = 2.7025482032898827e-05f; // ALPHA*R*ln2^2
static constexpr float  ZLO      = -3.0f;
static constexpr float  TABH     = 0.125f;
static constexpr float  IDXBIAS  = 24.0f;                 // -ZLO/h
static constexpr float  CUTBIAS  = 4.0f;                  // 24 - 8*ZCUT, ZCUT = 2.5

// ---------------- P0: prescale, koff-stuff, sort desc, pad ----------------
// ws[(c*COUT + o)*NPAD + j] : thp values sorted DESCENDING (active = prefix thp > cutp)
__global__ __launch_bounds__(256) void sort_theta_kernel(
    const float* __restrict__ theta, float* __restrict__ ws)
{
    int gid = blockIdx.x * 256 + threadIdx.x;   // o*CIN + c (theta layout)
    if (gid >= COUT * CIN) return;
    int o = gid >> 6, c = gid & 63;
    const float* tg = theta + (size_t)gid * 9;
    float v[NPAD];
#pragma unroll
    for (int k = 0; k < 9; ++k) {
        float thp = fmaf(tg[k], -MSC8, IDXBIAS);
        int dy = k / 3, dx = k - 3 * dy;
        uint32_t koff = (uint32_t)(dy * TROW + dx);      // in {0,1,2,36,37,38,72,73,74} <= 0x4A
        v[k] = __uint_as_float((__float_as_uint(thp) & ~0x7Fu) | koff);
    }
    for (int i = 1; i < 9; ++i) {               // insertion sort DESCENDING
        float key = v[i];
        int j = i - 1;
        while (j >= 0 && v[j] < key) { v[j + 1] = v[j]; --j; }
        v[j + 1] = key;
    }
    float pad = __uint_as_float(__float_as_uint(-1e30f) & ~0x7Fu);  // inactive, koff=0
    v[9] = pad; v[10] = pad; v[11] = pad;
    float* og = ws + (size_t)(c * COUT + o) * NPAD;
#pragma unroll
    for (int j = 0; j < NPAD; ++j) og[j] = v[j];
}

// ---------------- P1: per-(b, band, c) cut in thp units ----------------
// band m covers wave rows 2m,2m+1; window rows 2m-1..2m+2 clamped.
// cutp = CUTBIAS - max(window x, 0)*MSC8 ; active group iff any thp > cutp
__global__ __launch_bounds__(256) void bandcut_kernel(
    const float* __restrict__ x, float* __restrict__ bandcut)
{
    int t  = threadIdx.x;
    int bc = blockIdx.x;            // b*CIN + c
    const float4* xp = (const float4*)(x + (size_t)bc * PP);
    float4 v = xp[t];               // thread t: row t>>3, cols 4(t&7)..+3
    float m = fmaxf(fmaxf(v.x, v.y), fmaxf(v.z, v.w));
    m = fmaxf(m, __shfl_xor(m, 1));
    m = fmaxf(m, __shfl_xor(m, 2));
    m = fmaxf(m, __shfl_xor(m, 4));   // 8 threads of a row hold rowmax
    __shared__ float rmax[32];
    if ((t & 7) == 0) rmax[t >> 3] = m;
    __syncthreads();
    if (t < 16) {
        int r0 = max(2 * t - 1, 0), r3 = min(2 * t + 2, 31);
        float mm = rmax[r0];
        for (int r = r0 + 1; r <= r3; ++r) mm = fmaxf(mm, rmax[r]);
        mm = fmaxf(mm, 0.0f);         // zero-pad contributes xi = 0
        int b = bc >> 6, c = bc & 63;
        bandcut[((b * 16 + t) << 6) + c] = fmaf(mm, -MSC8, CUTBIAS);
    }
}

// ---------------- P2: f-table (duplicated pairs, fp64-evaluated) ----------------
__global__ __launch_bounds__(256) void ftable_kernel(float2* __restrict__ tab)
{
    int i = threadIdx.x;
    if (i >= TABN) return;
    double Z0 = (double)ZLO + (double)TABH * i;
    double Z1 = Z0 + (double)TABH;
    auto fd = [](double Z) {
        double E = exp2(Z);
        double a = log2(1.0 + E);
        double b = log2(1.0 + E * M2Nd);
        return a * a - b * b;
    };
    tab[i] = make_float2((float)fd(Z0), (float)fd(Z1));
}

// ---------------- main kernel ----------------
__global__ __launch_bounds__(256) void nlconv_kernel(
    const float* __restrict__ x,        // [B, CIN, 32, 32]
    const float* __restrict__ wst,      // sorted thp [c][o][NPAD]
    const float* __restrict__ wcut,     // cutp [b][band][c]
    const float2* __restrict__ ftabg,   // f-table pairs
    float* __restrict__ out)            // [B, COUT, 32, 32]
{
    __shared__ float  sxi[4 * TWSZ];    // per-wave 4x36 halo tiles + dump, 2368 B
    __shared__ float2 ftab[TABN];       // 1280 B

    const int t  = threadIdx.x;
    const int b  = blockIdx.x;
    const int pt = blockIdx.y;
    const int ot = blockIdx.z;
    const int w  = t >> 6;
    const int l  = t & 63;
    const int o0 = ot * OTILE;
    const int band = pt * 4 + w;
    const int rl = l >> 5, col = l & 31;

    if (t < TABN) ftab[t] = ftabg[t];

    // per-lane staging map: 3 entries e = l, l+64, l+128 over the 144-dword tile
    const int wbase = w * TWSZ;
    int   gofs[3];   // dword offset within a channel's 1024-px image
    float msc[3];    // MSC8 or 0 (halo/invalid)
    int   laddr[3];  // dword index into sxi
#pragma unroll
    for (int i = 0; i < 3; ++i) {
        int e  = l + 64 * i;
        bool valid = (e < 144);
        int ec = valid ? e : 144;           // dump slot for invalid third entries
        int r  = ec / TROW;
        int tc = ec - r * TROW;
        int grow = band * 2 - 1 + r;
        int gcol = tc - 1;
        bool inter = valid && (grow >= 0) && (grow < HH) && (gcol >= 0) && (gcol < WW) && (r < 4);
        gofs[i]  = (min(max(grow, 0), HH - 1) << 5) + min(max(gcol, 0), WW - 1);
        msc[i]   = inter ? MSC8 : 0.0f;
        laddr[i] = wbase + min(ec, TWSZ - 1);
    }

    // this wave's 64 channel cuts: lane c holds cutp[c]
    const float vcut = wcut[(size_t)((b * 16 + band) << 6) + l];

    // spread offsets for the ballot count (within one (c, o-tile) 96-float window)
    const int sp1 = (l >> 3) * NPAD + (l & 7);   // g = l>>3, j = l&7
    const int sp2 = (l & 7) * NPAD + 8;          // g = l&7,  j = 8

    const float* xc0 = x + (size_t)b * CIN * PP;
    const float* wso = wst + (size_t)o0 * NPAD;  // + c*COUT*NPAD
    const int xb = wbase + rl * TROW + col;      // body x base (dword)

    float acc[OTILE];
#pragma unroll
    for (int i = 0; i < OTILE; ++i) acc[i] = 0.0f;

    // prologue: xv(0) -> tile(0); xv <- c=1; f <- c=0
    float xv[3];
#pragma unroll
    for (int i = 0; i < 3; ++i) xv[i] = xc0[gofs[i]] * msc[i];
    float f1 = wso[sp1], f2 = wso[sp2];
#pragma unroll
    for (int i = 0; i < 3; ++i) sxi[laddr[i]] = xv[i];
#pragma unroll
    for (int i = 0; i < 3; ++i) xv[i] = xc0[PP + gofs[i]] * msc[i];

    __syncthreads();   // ftab ready (tiles are wave-private)

    for (int c = 0; c < CIN; ++c) {
        const float cutp = __uint_as_float(
            (uint32_t)__builtin_amdgcn_readlane((int)__float_as_uint(vcut), c));
        unsigned long long mA = __ballot(f1 > cutp);
        unsigned long long mB = __ballot(f2 > cutp);

        // prefetch next c's spread values
        {
            int cn = min(c + 1, CIN - 1);
            const float* wsn = wso + (size_t)cn * (COUT * NPAD);
            f1 = wsn[sp1];
            f2 = wsn[sp2];
        }

        const float* thc = wso + (size_t)c * (COUT * NPAD);

#pragma unroll
        for (int g = 0; g < 8; ++g) {
            int cnt = (int)__popcll(mA & (0xFFull << (8 * g)))
                    + (int)((mB >> g) & 1ull);
            int np = (cnt + 1) >> 1;           // pair iterations (<=5)
            asm volatile("" : "+s"(np));       // opaque: loop stays a real loop
            const float* gth = thc + g * NPAD;
            float2 pc = *(const float2*)gth;   // pair 0 (broadcast global load)
            float a = acc[g];
#pragma unroll 1
            for (int j = 0; j < np; ++j) {
                float2 pn = *(const float2*)(gth + 2 * j + 2);  // prefetch j+1 (<= floats 10,11)
                // body A
                {
                    int   ko = (int)(__float_as_uint(pc.x) & 0x7Fu);
                    float xa = sxi[xb + ko];             // ds_read, in-tile by construction
                    float u  = fmaxf(xa + pc.x, 0.0f);   // pads: -1e30 -> u = 0
                    int   i  = min((int)u, TABN - 2);
                    float fr = u - (float)i;             // >1 extrapolates the tail exactly-ish
                    float2 y = ftab[i];
                    a = fmaf(fr, y.y - y.x, y.x) + a;
                }
                // body B
                {
                    int   ko = (int)(__float_as_uint(pc.y) & 0x7Fu);
                    float xa = sxi[xb + ko];
                    float u  = fmaxf(xa + pc.y, 0.0f);
                    int   i  = min((int)u, TABN - 2);
                    float fr = u - (float)i;
                    float2 y = ftab[i];
                    a = fmaf(fr, y.y - y.x, y.x) + a;
                }
                pc = pn;
            }
            acc[g] = a;
        }

        // stage tile(c+1) from xv, then prefetch xv(c+2)
#pragma unroll
        for (int i = 0; i < 3; ++i) sxi[laddr[i]] = xv[i];
        {
            int c2 = min(c + 2, CIN - 1);
            const float* xcn = xc0 + (size_t)c2 * PP;
#pragma unroll
            for (int i = 0; i < 3; ++i) xv[i] = xcn[gofs[i]] * msc[i];
        }
    }

    float* ob = out + ((size_t)b * COUT + o0) * PP + pt * PTILE + t;
#pragma unroll
    for (int o = 0; o < OTILE; ++o) {
        float v = acc[o] * OUTSCALE;
        v = fminf(fmaxf(v, 0.0f), 9.0f);
        ob[(size_t)o * PP] = v;
    }
}

extern "C" void kernel_launch(void* const* d_in, const int* in_sizes, int n_in,
                              void* d_out, int out_size, void* d_ws, size_t ws_size,
                              hipStream_t stream) {
    const float* x     = (const float*)d_in[0];  // [32,64,32,32]
    const float* theta = (const float*)d_in[1];  // [128,64,3,3]
    float* out         = (float*)d_out;          // [32,128,32,32]

    float*  ws_theta = (float*)d_ws;                               // 393,216 B
    float*  ws_cut   = ws_theta + (size_t)CIN * COUT * NPAD;       // 131,072 B
    float2* ws_tab   = (float2*)(ws_cut + (size_t)BB * 16 * 64);   //   1,280 B

    sort_theta_kernel<<<dim3((COUT * CIN + 255) / 256), dim3(256), 0, stream>>>(theta, ws_theta);
    bandcut_kernel<<<dim3(BB * CIN), dim3(256), 0, stream>>>(x, ws_cut);
    ftable_kernel<<<dim3(1), dim3(256), 0, stream>>>(ws_tab);

    dim3 grid(BB, PP / PTILE, COUT / OTILE);     // 32 x 4 x 16 = 2048 blocks
    nlconv_kernel<<<grid, dim3(256), 0, stream>>>(x, ws_theta, ws_cut, ws_tab, out);
}

// Round 9
// 293.357 us; speedup vs baseline: 2.1146x; 1.0440x over previous
//
#include <hip/hip_runtime.h>
#include <math.h>
#include <stdint.h>

// Problem constants
#define BB    32
#define CIN   64
#define HH    32
#define WW    32
#define COUT  128
#define PP    1024      // HH*WW
#define OTILE 8         // output channels per block
#define PTILE 256       // pixels per block (4 waves x 64 px = 8 rows)
#define NPAD  12        // sorted theta list padded to 12 (3 pairs headroom)
#define TABN  160       // f-table knots
#define TROW  36        // tile row stride (34 cols + 2 slack)
#define TWSZ  148       // per-wave tile dwords (4*36 + dump + pad)

// Log2 domain: Z = (x - theta)*SCALEE, SCALEE = inv_denom*log2(e) = 19.2359
// Table coordinate u = (Z - ZLO)/h = 8Z + 24 = x*MSC8 + thp, thp = 24 - theta*MSC8
static constexpr float  MSC8     = 153.88747102815611f;   // SCALEE * 8
static constexpr double M2Nd     = 0.26359713811572677;   // 2^-SBITS
static constexpr float  OUTSCALE = 2.7025482032898827e-05f; // ALPHA*R*ln2^2
static constexpr float  ZLO      = -3.0f;
static constexpr float  TABH     = 0.125f;
static constexpr float  IDXBIAS  = 24.0f;                 // -ZLO/h
static constexpr float  CUTBIAS  = 4.0f;                  // 24 - 8*ZCUT, ZCUT = 2.5

// ---------------- P0: prescale, koff-stuff, sort desc, pad ----------------
// ws[(c*COUT + o)*NPAD + j] : thp values sorted DESCENDING (active = prefix thp > cutp)
__global__ __launch_bounds__(256) void sort_theta_kernel(
    const float* __restrict__ theta, float* __restrict__ ws)
{
    int gid = blockIdx.x * 256 + threadIdx.x;   // o*CIN + c (theta layout)
    if (gid >= COUT * CIN) return;
    int o = gid >> 6, c = gid & 63;
    const float* tg = theta + (size_t)gid * 9;
    float v[NPAD];
#pragma unroll
    for (int k = 0; k < 9; ++k) {
        float thp = fmaf(tg[k], -MSC8, IDXBIAS);
        int dy = k / 3, dx = k - 3 * dy;
        uint32_t koff = (uint32_t)(dy * TROW + dx);      // in {0,1,2,36,37,38,72,73,74} <= 0x4A
        v[k] = __uint_as_float((__float_as_uint(thp) & ~0x7Fu) | koff);
    }
    for (int i = 1; i < 9; ++i) {               // insertion sort DESCENDING
        float key = v[i];
        int j = i - 1;
        while (j >= 0 && v[j] < key) { v[j + 1] = v[j]; --j; }
        v[j + 1] = key;
    }
    float pad = __uint_as_float(__float_as_uint(-1e30f) & ~0x7Fu);  // inactive, koff=0
    v[9] = pad; v[10] = pad; v[11] = pad;
    float* og = ws + (size_t)(c * COUT + o) * NPAD;
#pragma unroll
    for (int j = 0; j < NPAD; ++j) og[j] = v[j];
}

// ---------------- P1: per-(b, band, c) cut in thp units ----------------
__global__ __launch_bounds__(256) void bandcut_kernel(
    const float* __restrict__ x, float* __restrict__ bandcut)
{
    int t  = threadIdx.x;
    int bc = blockIdx.x;            // b*CIN + c
    const float4* xp = (const float4*)(x + (size_t)bc * PP);
    float4 v = xp[t];               // thread t: row t>>3, cols 4(t&7)..+3
    float m = fmaxf(fmaxf(v.x, v.y), fmaxf(v.z, v.w));
    m = fmaxf(m, __shfl_xor(m, 1));
    m = fmaxf(m, __shfl_xor(m, 2));
    m = fmaxf(m, __shfl_xor(m, 4));   // 8 threads of a row hold rowmax
    __shared__ float rmax[32];
    if ((t & 7) == 0) rmax[t >> 3] = m;
    __syncthreads();
    if (t < 16) {
        int r0 = max(2 * t - 1, 0), r3 = min(2 * t + 2, 31);
        float mm = rmax[r0];
        for (int r = r0 + 1; r <= r3; ++r) mm = fmaxf(mm, rmax[r]);
        mm = fmaxf(mm, 0.0f);         // zero-pad contributes xi = 0
        int b = bc >> 6, c = bc & 63;
        bandcut[((b * 16 + t) << 6) + c] = fmaf(mm, -MSC8, CUTBIAS);
    }
}

// ---------------- P2: coefficient table, fp64-evaluated ----------------
// tab[i] = (c0, c1) with f(u) ~= c0 + c1*u on [i, i+1]; for u > 159 the i=158
// segment extrapolates linearly — its slope equals the asymptote 2S*h to ~1e-6,
// same behavior as R7's fr>1 lerp extension (verified passing).
__global__ __launch_bounds__(256) void ftable_kernel(float2* __restrict__ tab)
{
    int i = threadIdx.x;
    if (i >= TABN) return;
    double Z0 = (double)ZLO + (double)TABH * i;
    double Z1 = Z0 + (double)TABH;
    auto fd = [](double Z) {
        double E = exp2(Z);
        double a = log2(1.0 + E);
        double b = log2(1.0 + E * M2Nd);
        return a * a - b * b;
    };
    double y0 = fd(Z0), y1 = fd(Z1);
    double c1 = y1 - y0;                 // per-u slope (segment width = 1 u)
    double c0 = y0 - (double)i * c1;
    tab[i] = make_float2((float)c0, (float)c1);
}

// ---------------- main kernel ----------------
__global__ __launch_bounds__(256) void nlconv_kernel(
    const float* __restrict__ x,        // [B, CIN, 32, 32]
    const float* __restrict__ wst,      // sorted thp [c][o][NPAD]
    const float* __restrict__ wcut,     // cutp [b][band][c]
    const float2* __restrict__ ftabg,   // coefficient table
    float* __restrict__ out)            // [B, COUT, 32, 32]
{
    __shared__ float  sxi[4 * TWSZ];    // per-wave 4x36 halo tiles + dump, 2368 B
    __shared__ float2 ftab[TABN];       // 1280 B

    const int t  = threadIdx.x;
    const int b  = blockIdx.x;
    const int pt = blockIdx.y;
    const int ot = blockIdx.z;
    const int w  = t >> 6;
    const int l  = t & 63;
    const int o0 = ot * OTILE;
    const int band = pt * 4 + w;
    const int rl = l >> 5, col = l & 31;

    if (t < TABN) ftab[t] = ftabg[t];

    // per-lane staging map: 3 entries e = l, l+64, l+128 over the 144-dword tile
    const int wbase = w * TWSZ;
    int   gofs[3];   // dword offset within a channel's 1024-px image
    float msc[3];    // MSC8 or 0 (halo/invalid)
    int   laddr[3];  // dword index into sxi
#pragma unroll
    for (int i = 0; i < 3; ++i) {
        int e  = l + 64 * i;
        bool valid = (e < 144);
        int ec = valid ? e : 144;           // dump slot for invalid third entries
        int r  = ec / TROW;
        int tc = ec - r * TROW;
        int grow = band * 2 - 1 + r;
        int gcol = tc - 1;
        bool inter = valid && (grow >= 0) && (grow < HH) && (gcol >= 0) && (gcol < WW) && (r < 4);
        gofs[i]  = (min(max(grow, 0), HH - 1) << 5) + min(max(gcol, 0), WW - 1);
        msc[i]   = inter ? MSC8 : 0.0f;
        laddr[i] = wbase + min(ec, TWSZ - 1);
    }

    // this wave's 64 channel cuts: lane c holds cutp[c]
    const float vcut = wcut[(size_t)((b * 16 + band) << 6) + l];

    // spread offsets for the ballot count (within one (c, o-tile) 96-float window)
    const int sp1 = (l >> 3) * NPAD + (l & 7);   // g = l>>3, j = l&7
    const int sp2 = (l & 7) * NPAD + 8;          // g = l&7,  j = 8

    const float* xc0 = x + (size_t)b * CIN * PP;
    const float* wso = wst + (size_t)o0 * NPAD;  // + c*COUT*NPAD
    const int xb = wbase + rl * TROW + col;      // body x base (dword)

    float acc[OTILE];
#pragma unroll
    for (int i = 0; i < OTILE; ++i) acc[i] = 0.0f;

    // prologue: xv(0) -> tile(0); xv <- c=1; f <- c=0
    float xv[3];
#pragma unroll
    for (int i = 0; i < 3; ++i) xv[i] = xc0[gofs[i]] * msc[i];
    float f1 = wso[sp1], f2 = wso[sp2];
#pragma unroll
    for (int i = 0; i < 3; ++i) sxi[laddr[i]] = xv[i];
#pragma unroll
    for (int i = 0; i < 3; ++i) xv[i] = xc0[PP + gofs[i]] * msc[i];

    __syncthreads();   // ftab ready (tiles are wave-private)

    for (int c = 0; c < CIN; ++c) {
        const float cutp = __uint_as_float(
            (uint32_t)__builtin_amdgcn_readlane((int)__float_as_uint(vcut), c));
        unsigned long long mA = __ballot(f1 > cutp);
        unsigned long long mB = __ballot(f2 > cutp);

        // prefetch next c's spread values
        {
            int cn = min(c + 1, CIN - 1);
            const float* wsn = wso + (size_t)cn * (COUT * NPAD);
            f1 = wsn[sp1];
            f2 = wsn[sp2];
        }

        const float* thc = wso + (size_t)c * (COUT * NPAD);

#pragma unroll
        for (int g = 0; g < 8; ++g) {
            int cnt = (int)__popcll(mA & (0xFFull << (8 * g)))
                    + (int)((mB >> g) & 1ull);
            int np = (cnt + 1) >> 1;           // pair iterations (<=5)
            asm volatile("" : "+s"(np));       // opaque: loop stays a real loop
            const float* gth = thc + g * NPAD;
            float2 pc = *(const float2*)gth;   // pair 0 (broadcast global load)
            float a = acc[g];
#pragma unroll 1
            for (int j = 0; j < np; ++j) {
                float2 pn = *(const float2*)(gth + 2 * j + 2);  // prefetch j+1 (<= floats 10,11)
                // body A: ~9 VALU + 2 LDS; i=158 segment extrapolates the tail
                {
                    int   ko = (int)(__float_as_uint(pc.x) & 0x7Fu);
                    float xa = sxi[xb + ko];                   // ds_read
                    float u  = fmaxf(xa + pc.x, 0.0f);         // pads -> u=0 -> tv~f(-3)~0
                    int   i  = min((int)u, TABN - 2);          // NO upper u clamp
                    float2 cf = ftab[i];                       // ds_read_b64 (c0, c1)
                    a = fmaf(cf.y, u, a) + cf.x;               // a += c0 + c1*u
                }
                // body B
                {
                    int   ko = (int)(__float_as_uint(pc.y) & 0x7Fu);
                    float xa = sxi[xb + ko];
                    float u  = fmaxf(xa + pc.y, 0.0f);
                    int   i  = min((int)u, TABN - 2);
                    float2 cf = ftab[i];
                    a = fmaf(cf.y, u, a) + cf.x;
                }
                pc = pn;
            }
            acc[g] = a;
        }

        // stage tile(c+1) from xv, then prefetch xv(c+2)
#pragma unroll
        for (int i = 0; i < 3; ++i) sxi[laddr[i]] = xv[i];
        {
            int c2 = min(c + 2, CIN - 1);
            const float* xcn = xc0 + (size_t)c2 * PP;
#pragma unroll
            for (int i = 0; i < 3; ++i) xv[i] = xcn[gofs[i]] * msc[i];
        }
    }

    float* ob = out + ((size_t)b * COUT + o0) * PP + pt * PTILE + t;
#pragma unroll
    for (int o = 0; o < OTILE; ++o) {
        float v = acc[o] * OUTSCALE;
        v = fminf(fmaxf(v, 0.0f), 9.0f);
        ob[(size_t)o * PP] = v;
    }
}

extern "C" void kernel_launch(void* const* d_in, const int* in_sizes, int n_in,
                              void* d_out, int out_size, void* d_ws, size_t ws_size,
                              hipStream_t stream) {
    const float* x     = (const float*)d_in[0];  // [32,64,32,32]
    const float* theta = (const float*)d_in[1];  // [128,64,3,3]
    float* out         = (float*)d_out;          // [32,128,32,32]

    float*  ws_theta = (float*)d_ws;                               // 393,216 B
    float*  ws_cut   = ws_theta + (size_t)CIN * COUT * NPAD;       // 131,072 B
    float2* ws_tab   = (float2*)(ws_cut + (size_t)BB * 16 * 64);   //   1,280 B

    sort_theta_kernel<<<dim3((COUT * CIN + 255) / 256), dim3(256), 0, stream>>>(theta, ws_theta);
    bandcut_kernel<<<dim3(BB * CIN), dim3(256), 0, stream>>>(x, ws_cut);
    ftable_kernel<<<dim3(1), dim3(256), 0, stream>>>(ws_tab);

    dim3 grid(BB, PP / PTILE, COUT / OTILE);     // 32 x 4 x 16 = 2048 blocks
    nlconv_kernel<<<grid, dim3(256), 0, stream>>>(x, ws_theta, ws_cut, ws_tab, out);
}